// Round 12
// baseline (72.526 us; speedup 1.0000x reference)
//
#include <hip/hip_runtime.h>
#include <hip/hip_bf16.h>

// Problem constants (from reference):
// B=2, N=6, D=120, H=32, W=88, C=128, Z=1, HO=128, WO=128
#define HW_    2816
#define C_     128
#define BN_    12
#define SPAT_  16384
#define CELLS_ 32768
#define CPB_   128         // cells per main block (128 consecutive sp positions)

// prep_k block-range dispatch
#define TF_BX     88                       // HW_/32
#define TF_BY     4                        // C_/32
#define TF_BLOCKS (TF_BX * TF_BY * BN_)    // 4224 transpose tiles
#define PG_BLOCKS 512                      // pregather: 512*256*8 = 1,048,576 slots
#define IV_BLOCKS 128                      // 128*256 = 32768 >= n_intervals

// round-to-nearest-even f32 -> bf16 (as uint in [0,0xffff]); finite values
__device__ __forceinline__ unsigned int f2bf_rne(float x) {
    const unsigned int u = __float_as_uint(x);
    return (u + 0x7fffu + ((u >> 16) & 1u)) >> 16;
}

// ---------------------------------------------------------------------------
// Fused prep:
//   [0, TF)      feat [BN,C,HW] f32 -> featT [BN,HW,C] bf16
//   [TF, +PG)    pair[i] = bf16(depth[rd[i]])<<16 | rf[i]  (rf < 33792 fits u16)
//                8 gathers in flight per thread (r11: 4-deep under-hid latency)
//   [.., +IV)    iv4[ivl] = {start, len, cell, 0}; map[cell]=ivl, gaps -> -1
//                (race-free: each thread owns [cell, next_cell); rb sorted)
// ---------------------------------------------------------------------------
__global__ __launch_bounds__(256) void prep_k(
        const float* __restrict__ feat, __hip_bfloat16* __restrict__ featT,
        const float* __restrict__ depth, const int* __restrict__ rd,
        const int* __restrict__ rf, unsigned int* __restrict__ pair, int n_points,
        const int* __restrict__ istart, const int* __restrict__ ilen,
        const int* __restrict__ rb, int4* __restrict__ iv4,
        int* __restrict__ map, int n_intervals) {
    __shared__ float tile[32][33];
    const int bid = blockIdx.x;
    const int tid = threadIdx.x;

    if (bid < TF_BLOCKS) {
        const int bn  = bid / (TF_BX * TF_BY);
        const int r   = bid - bn * (TF_BX * TF_BY);
        const int c0  = (r / TF_BX) * 32;
        const int hw0 = (r - (r / TF_BX) * TF_BX) * 32;
        const int x = tid & 31, y = tid >> 5;           // y in 0..7
        const float* src = feat + ((size_t)bn * C_ + c0) * HW_ + hw0;
        #pragma unroll
        for (int yy = y; yy < 32; yy += 8)
            tile[yy][x] = src[(size_t)yy * HW_ + x];     // coalesced along hw
        __syncthreads();
        __hip_bfloat16* dst = featT + ((size_t)bn * HW_ + hw0) * C_ + c0;
        #pragma unroll
        for (int yy = y; yy < 32; yy += 8)
            dst[(size_t)yy * C_ + x] = __float2bfloat16(tile[x][yy]);  // coalesced along c
    } else if (bid < TF_BLOCKS + PG_BLOCKS) {
        const int t = (bid - TF_BLOCKS) * 256 + tid;     // 0..131071
        const int S = PG_BLOCKS * 256;                   // 131072
        int idx[8], rfv[8];
        float v[8];
        #pragma unroll
        for (int u = 0; u < 8; ++u) {
            const int ii = t + u * S;
            const int cl = ii < n_points ? ii : t;       // clamp addr (u=0 valid)
            idx[u] = rd[cl];
            rfv[u] = rf[cl];
        }
        #pragma unroll
        for (int u = 0; u < 8; ++u) v[u] = depth[idx[u]];   // 8 gathers in flight
        #pragma unroll
        for (int u = 0; u < 8; ++u) {
            const int ii = t + u * S;
            if (ii < n_points)
                pair[ii] = (f2bf_rne(v[u]) << 16) | (unsigned)rfv[u];
        }
    } else {
        const int ivl = (bid - TF_BLOCKS - PG_BLOCKS) * 256 + tid;
        if (ivl < n_intervals) {
            const int s = istart[ivl];
            const int c = rb[s];
            iv4[ivl] = make_int4(s, ilen[ivl], c, 0);
            map[c] = ivl;
            const int cnext = (ivl + 1 < n_intervals) ? rb[istart[ivl + 1]] : CELLS_;
            for (int cc = c + 1; cc < cnext; ++cc) map[cc] = -1;   // gaps (~rare)
            if (ivl == 0) for (int cc = 0; cc < c; ++cc) map[cc] = -1;
        }
    }
}

// ---------------------------------------------------------------------------
// Main, direct-to-out: block = (128-cell range, channel QUARTER).
// blockIdx.x&3 -> XCD (bid%8 round-robin): each XCD gathers only a 2.16 MB
// featT quarter-table, which FITS its 4 MB L2 with room (r11 lesson: the
// 4.33 MB half-table did NOT fit -> thrash). pair/out are streaming
// (each point belongs to exactly one block -> read-once, no residency need).
// 512 threads = 8 waves x 16 groups of 4 lanes; group owns ONE cell serially
// (no shfl reduce), 4 slots in flight; lane owns 8 channels of the quarter
// (uint4 = bf16x8; 4 lanes x 16B = 64B quarter-row). Per feat-load instr:
// 16 independent rows (1KB) in flight. Results staged f32 in LDS [128][36];
// cooperative store: 64 lanes x 4B = 256B contiguous per instr (r6-proven
// clean; 64B segments are 17x amplified, r5). Empty cells -> LDS zeros;
// every out element written exactly once => no zero pass, no transpose.
// ---------------------------------------------------------------------------
__global__ __launch_bounds__(512, 4) void bevpool_cells_k(
        const unsigned int* __restrict__ pair,
        const uint4* __restrict__ featT,
        const int4* __restrict__ iv4,
        const int* __restrict__ map,
        float* __restrict__ out) {
    __shared__ float lds[CPB_][36];           // 32 ch + pad; 18.4 KB
    const int q     = blockIdx.x & 3;         // channel quarter
    const int cb    = blockIdx.x >> 2;        // 0..255
    const int cell0 = cb * CPB_;
    const int tid   = threadIdx.x;

    for (int i = tid; i < CPB_ * 36; i += 512) (&lds[0][0])[i] = 0.f;
    __syncthreads();

    const int w    = tid >> 6;                // wave 0..7
    const int lane = tid & 63;
    const int g    = lane >> 2;               // group 0..15 (one cell each)
    const int sl   = lane & 3;                // channel chunk within quarter
    const int lc   = w * 16 + g;              // local cell 0..127
    const size_t hoff = (size_t)(q * 4 + sl); // uint4 offset within 256B row

    const int m  = map[cell0 + lc];
    const int4 v = iv4[m < 0 ? 0 : m];

    if (m >= 0) {
        const int start = v.x;
        const int end   = v.x + v.y;
        float acc[8] = {0.f, 0.f, 0.f, 0.f, 0.f, 0.f, 0.f, 0.f};

        for (int i = start; i < end; i += 4) {
            int cl_[4];
            unsigned pr_[4];
            float d_[4];
            uint4 f_[4];
            #pragma unroll
            for (int u = 0; u < 4; ++u) {
                const int ii = i + u;
                cl_[u] = (ii < end) ? ii : i;          // clamp to valid address
            }
            #pragma unroll
            for (int u = 0; u < 4; ++u) pr_[u] = pair[cl_[u]];  // 1 stream load/slot
            #pragma unroll
            for (int u = 0; u < 4; ++u) d_[u] = __uint_as_float(pr_[u] & 0xffff0000u);
            #pragma unroll
            for (int u = 1; u < 4; ++u) d_[u] = (i + u < end) ? d_[u] : 0.f;
            #pragma unroll
            for (int u = 0; u < 4; ++u)
                f_[u] = featT[(size_t)(pr_[u] & 0xffffu) * 16 + hoff];
            #pragma unroll
            for (int u = 0; u < 4; ++u) {
                const float d = d_[u];
                acc[0] = fmaf(d, __uint_as_float(f_[u].x << 16),         acc[0]);
                acc[1] = fmaf(d, __uint_as_float(f_[u].x & 0xffff0000u), acc[1]);
                acc[2] = fmaf(d, __uint_as_float(f_[u].y << 16),         acc[2]);
                acc[3] = fmaf(d, __uint_as_float(f_[u].y & 0xffff0000u), acc[3]);
                acc[4] = fmaf(d, __uint_as_float(f_[u].z << 16),         acc[4]);
                acc[5] = fmaf(d, __uint_as_float(f_[u].z & 0xffff0000u), acc[5]);
                acc[6] = fmaf(d, __uint_as_float(f_[u].w << 16),         acc[6]);
                acc[7] = fmaf(d, __uint_as_float(f_[u].w & 0xffff0000u), acc[7]);
            }
        }
        #pragma unroll
        for (int c = 0; c < 8; ++c) lds[lc][sl * 8 + c] = acc[c];
    }
    __syncthreads();

    // cooperative store: wave instr = 64 lanes x 4B = 256B contiguous (clean)
    const int cl  = tid & 127;                // local cell 0..127 (2 waves per chb)
    const int chb = tid >> 7;                 // 0..3
    const int b   = cell0 >> 14;              // cell0 / SPAT_
    const int sp0 = cell0 & (SPAT_ - 1);
    float* obase = out + ((size_t)b * C_ + q * 32) * SPAT_ + sp0;
    #pragma unroll
    for (int it = 0; it < 8; ++it) {
        const int ch = chb + 4 * it;          // 0..31 within the quarter
        obase[(size_t)ch * SPAT_ + cl] = lds[cl][ch];
    }
}

// ---------------------------------------------------------------------------
// Fallback (ws too small): original-layout reads, scattered stores.
// ---------------------------------------------------------------------------
__global__ __launch_bounds__(256) void bevpool_fallback_k(const float* __restrict__ depth,
                                                          const float* __restrict__ feat,
                                                          const int* __restrict__ rd_arr,
                                                          const int* __restrict__ rf_arr,
                                                          const int* __restrict__ rb,
                                                          const int* __restrict__ istart,
                                                          const int* __restrict__ ilen,
                                                          float* __restrict__ out,
                                                          int n_intervals) {
    const int wave = (int)((blockIdx.x * blockDim.x + threadIdx.x) >> 6);
    const int lane = threadIdx.x & 63;
    if (wave >= n_intervals) return;
    const int start = istart[wave];
    const int len   = ilen[wave];
    const int cell  = rb[start];
    float ax = 0.f, ay = 0.f;
    const int end = start + len;
    for (int i = start; i < end; ++i) {
        const int rfi = rf_arr[i];
        const int bn  = rfi / HW_;
        const int hw  = rfi - bn * HW_;
        const float d = depth[rd_arr[i]];
        const float* frow = feat + (size_t)bn * (C_ * HW_) + hw;
        ax = fmaf(d, frow[(size_t)(2 * lane)     * HW_], ax);
        ay = fmaf(d, frow[(size_t)(2 * lane + 1) * HW_], ay);
    }
    const int b  = cell >> 14;
    const int sp = cell & (SPAT_ - 1);
    float* o = out + (size_t)b * ((size_t)C_ * SPAT_) + sp;
    o[(size_t)(2 * lane)     * SPAT_] = ax;
    o[(size_t)(2 * lane + 1) * SPAT_] = ay;
}

extern "C" void kernel_launch(void* const* d_in, const int* in_sizes, int n_in,
                              void* d_out, int out_size, void* d_ws, size_t ws_size,
                              hipStream_t stream) {
    const float* depth  = (const float*)d_in[0];
    const float* feat   = (const float*)d_in[1];
    const int*   rd     = (const int*)d_in[2];
    const int*   rf     = (const int*)d_in[3];
    const int*   rb     = (const int*)d_in[4];
    const int*   istart = (const int*)d_in[5];
    const int*   ilen   = (const int*)d_in[6];
    float*       out    = (float*)d_out;
    const int n_intervals = in_sizes[5];
    const int n_points    = in_sizes[2];

    const size_t featT_bytes = (size_t)BN_ * HW_ * C_ * sizeof(__hip_bfloat16); // 8.65 MB
    const size_t pair_bytes  = ((size_t)n_points * sizeof(unsigned int) + 15) & ~(size_t)15;
    const size_t iv4_bytes   = (size_t)CELLS_ * sizeof(int4);                   // 0.52 MB
    const size_t map_bytes   = (size_t)CELLS_ * sizeof(int);                    // 0.13 MB

    if (ws_size >= featT_bytes + pair_bytes + iv4_bytes + map_bytes &&
        n_intervals <= CELLS_) {
        __hip_bfloat16* featT = (__hip_bfloat16*)d_ws;
        unsigned int*   pair  = (unsigned int*)((char*)d_ws + featT_bytes);
        int4*           iv4   = (int4*)((char*)d_ws + featT_bytes + pair_bytes);
        int*            map   = (int*)((char*)d_ws + featT_bytes + pair_bytes + iv4_bytes);

        const int prep_blocks = TF_BLOCKS + PG_BLOCKS + IV_BLOCKS;
        prep_k<<<prep_blocks, 256, 0, stream>>>(
            feat, featT, depth, rd, rf, pair, n_points,
            istart, ilen, rb, iv4, map, n_intervals);

        bevpool_cells_k<<<(CELLS_ / CPB_) * 4, 512, 0, stream>>>(
            pair, (const uint4*)featT, iv4, map, out);
    } else {
        hipMemsetAsync(out, 0, (size_t)out_size * sizeof(float), stream);
        const int blocks = (n_intervals + 3) / 4;
        bevpool_fallback_k<<<blocks, 256, 0, stream>>>(
            depth, feat, rd, rf, rb, istart, ilen, out, n_intervals);
    }
}